// Round 17
// baseline (161.178 us; speedup 1.0000x reference)
//
#include <hip/hip_runtime.h>
#include <cmath>

#define NPTS 8192
#define DIM 64
#define BT 128
#define KSTR 132         // float word stride per ROW of Ks (row-major)

// ws layout (float offsets)
#define LEAF_F   0
#define LEAF_N   (3 * 8192 * 64)          // layout [z][cb][row]
#define ROWS_F   (LEAF_F + LEAF_N)
#define ROWS_N   (3 * 8192)
#define MEANS_F  (ROWS_F + ROWS_N)
#define CNT_F    (MEANS_F + 3)
#define NX_F     ((CNT_F + 1 + 3) & ~3)   // 16B-align
#define NY_F     (NX_F + 8192)
#define SPLIT_F  (NY_F + 8192)
#define SPLIT_ELEMS (NPTS * DIM)

// frag-major split layout: [rowtile t16][kc 0..1][quad 0..3][mrow 0..15][8]

typedef short bf16x8 __attribute__((ext_vector_type(8)));
typedef float f32x4  __attribute__((ext_vector_type(4)));
typedef float f32x2  __attribute__((ext_vector_type(2)));

__device__ __forceinline__ unsigned short f32_bf16_rne(float f) {
    unsigned u = __float_as_uint(f);
    return (unsigned short)((u + 0x7FFFu + ((u >> 16) & 1u)) >> 16);
}
__device__ __forceinline__ float bf16_f32(unsigned short h) {
    return __uint_as_float(((unsigned)h) << 16);
}

// ---- fused prep (64x256): bf16 hi/lo split (frag-major) + norms + cnt=0
__global__ void prep_kernel(const float* __restrict__ x, const float* __restrict__ y,
                            unsigned short* __restrict__ Xh, unsigned short* __restrict__ Xl,
                            unsigned short* __restrict__ Yh, unsigned short* __restrict__ Yl,
                            float* __restrict__ nx, float* __restrict__ ny,
                            unsigned* __restrict__ cnt) {
    int r = blockIdx.x * 256 + threadIdx.x;   // 0..16383
    if (r == 0) *cnt = 0u;
    int isY = r >= NPTS;
    int rr = isY ? r - NPTS : r;
    const float4* Rg = (const float4*)((isY ? y : x) + (size_t)rr * DIM);
    unsigned short* Hh = isY ? Yh : Xh;
    unsigned short* Hl = isY ? Yl : Xl;
    const int t16 = rr >> 4, mrow = rr & 15;
    float s = 0.f;
    #pragma unroll
    for (int k4 = 0; k4 < 16; ++k4) {
        float4 v = Rg[k4];
        ushort4 h, l;
        h.x = f32_bf16_rne(v.x); l.x = f32_bf16_rne(v.x - bf16_f32(h.x));
        h.y = f32_bf16_rne(v.y); l.y = f32_bf16_rne(v.y - bf16_f32(h.y));
        h.z = f32_bf16_rne(v.z); l.z = f32_bf16_rne(v.z - bf16_f32(h.z));
        h.w = f32_bf16_rne(v.w); l.w = f32_bf16_rne(v.w - bf16_f32(h.w));
        int off = t16 * 1024 + (k4 >> 3) * 512 + ((k4 >> 1) & 3) * 128 + mrow * 8 + (k4 & 1) * 4;
        *(ushort4*)(Hh + off) = h;
        *(ushort4*)(Hl + off) = l;
        s = fmaf(v.x, v.x, s); s = fmaf(v.y, v.y, s);
        s = fmaf(v.z, v.z, s); s = fmaf(v.w, v.w, s);
    }
    if (isY) ny[rr] = s; else nx[rr] = s;
}

// ---- main tile kernel: R14 row-major Ks; row chains paired (b64 reads,
//      in-thread first tree level). All chain value-orders bit-identical.
__global__ __launch_bounds__(512, 4) void mmd_tile_kernel(
    const unsigned short* __restrict__ Xh, const unsigned short* __restrict__ Xl,
    const unsigned short* __restrict__ Yh, const unsigned short* __restrict__ Yl,
    const float* __restrict__ nx, const float* __restrict__ ny,
    float* __restrict__ leafs)
{
    const int gi = blockIdx.x;             // 0..64
    const int gj = blockIdx.y;             // 0..63
    int zz, bx, by;
    if (blockIdx.z == 1) {
        if (gi >= 64) return;
        zz = 2; bx = gi; by = gj;
    } else if (gi > gj) {
        zz = 0; by = gj; bx = gi - 1;
    } else {
        zz = 1; by = gi; bx = gj;
    }

    __shared__ __align__(16) float Ks[128 * KSTR];   // row-major: Ks[row*KSTR+col]
    __shared__ float sqA[BT];
    __shared__ float sqB[BT];

    const int t = threadIdx.x;
    const size_t arow = (size_t)by * BT;
    const size_t brow = (size_t)bx * BT;
    const int cb = bx;

    const unsigned short* pAh = (zz == 1) ? Yh : Xh;
    const unsigned short* pAl = (zz == 1) ? Yl : Xl;
    const unsigned short* pBh = (zz == 0) ? Xh : Yh;
    const unsigned short* pBl = (zz == 0) ? Xl : Yl;

    if (t < 256) {
        const float* nA = (zz == 1) ? ny : nx;
        const float* nB = (zz == 0) ? nx : ny;
        if (t < BT) sqA[t] = nA[arow + t];
        else        sqB[t - BT] = nB[brow + t - BT];
    }
    __syncthreads();

    const int lane = t & 63;
    const int wv   = t >> 6;               // 0..7
    const int mrow = lane & 15;
    const int quad = lane >> 4;
    const int rblk = (wv & 3) << 5;        // 0,32,64,96
    const int cblk = (wv >> 2) << 6;       // 0,64

    const int aT = by * 8 + (wv & 3) * 2;
    const int bT = bx * 8 + (wv >> 2) * 4;
    const int lsub = quad * 128 + mrow * 8;

    bf16x8 fAh[2][2], fAl[2][2];
    #pragma unroll
    for (int rt = 0; rt < 2; ++rt)
        #pragma unroll
        for (int kc = 0; kc < 2; ++kc) {
            int off = (aT + rt) * 1024 + kc * 512 + lsub;
            fAh[rt][kc] = *(const bf16x8*)(pAh + off);
            fAl[rt][kc] = *(const bf16x8*)(pAl + off);
        }

    f32x4 acc[2][4];
    #pragma unroll
    for (int rt = 0; rt < 2; ++rt)
        #pragma unroll
        for (int ct = 0; ct < 4; ++ct)
            acc[rt][ct] = (f32x4){0.f, 0.f, 0.f, 0.f};

    #pragma unroll
    for (int ct = 0; ct < 4; ++ct) {
        int boff = (bT + ct) * 1024 + lsub;
        bf16x8 bh0 = *(const bf16x8*)(pBh + boff);
        bf16x8 bh1 = *(const bf16x8*)(pBh + boff + 512);
        bf16x8 bl0 = *(const bf16x8*)(pBl + boff);
        bf16x8 bl1 = *(const bf16x8*)(pBl + boff + 512);
        #pragma unroll
        for (int rt = 0; rt < 2; ++rt) {
            f32x4 c = acc[rt][ct];
            // identical 6-pass order per accumulator as R8-R16
            c = __builtin_amdgcn_mfma_f32_16x16x32_bf16(fAh[rt][0], bh0, c, 0, 0, 0);
            c = __builtin_amdgcn_mfma_f32_16x16x32_bf16(fAh[rt][0], bl0, c, 0, 0, 0);
            c = __builtin_amdgcn_mfma_f32_16x16x32_bf16(fAl[rt][0], bh0, c, 0, 0, 0);
            c = __builtin_amdgcn_mfma_f32_16x16x32_bf16(fAh[rt][1], bh1, c, 0, 0, 0);
            c = __builtin_amdgcn_mfma_f32_16x16x32_bf16(fAh[rt][1], bl1, c, 0, 0, 0);
            c = __builtin_amdgcn_mfma_f32_16x16x32_bf16(fAl[rt][1], bh1, c, 0, 0, 0);
            acc[rt][ct] = c;
        }
    }

    // ---- epilogue: k = exp2f(sqd * -log2e/4096) (identical to R14)
    const float SCL = (float)(-1.4426950408889634 / 4096.0);
    #pragma unroll
    for (int rt = 0; rt < 2; ++rt)
        #pragma unroll
        for (int ct = 0; ct < 4; ++ct)
            #pragma unroll
            for (int i = 0; i < 4; ++i) {
                int row = rblk + rt * 16 + quad * 4 + i;
                int col = cblk + ct * 16 + mrow;
                float d  = acc[rt][ct][i];
                float s2 = sqA[row] + sqB[col];
                float sqd = s2 - 2.0f * d;
                Ks[row * KSTR + col] = exp2f(sqd * SCL);
            }
    __syncthreads();

    // ---- row chains, paired: thread -> (row, 2tp) and (row, 2tp+1) via b64.
    //      In-thread add = numpy tree level 1; 2 shfl levels; writer lane's
    //      combine order matches ((r0+r1)+(r2+r3))+((r4+r5)+(r6+r7)) exactly.
    {
        int row = t >> 2;             // 0..127
        int tp  = t & 3;              // chain pair 0..3 (tt = 2tp, 2tp+1)
        const float* base = &Ks[row * KSTR + 2 * tp];
        f32x2 v0 = *(const f32x2*)base;
        float se = v0.x, so = v0.y;
        #pragma unroll
        for (int q = 1; q < 16; ++q) {
            f32x2 v = *(const f32x2*)(base + 8 * q);
            se += v.x; so += v.y;     // each chain in q-ascending order
        }
        float s01 = se + so;          // tree level 1 (exact numpy pairing)
        float p;
        p = __shfl_xor(s01, 1); float s = s01 + p;   // level 2 (writer order ok)
        p = __shfl_xor(s, 2);   s = s + p;           // level 3
        if (tp == 0)
            leafs[((size_t)zz * 64 + cb) * 8192 + arow + row] = s;
    }

    // ---- mirror tile's leaf sums (identical to R14: scalar col-stride reads)
    if (zz < 2 && bx > by) {
        float mleaf[2];
        #pragma unroll
        for (int j = 0; j < 2; ++j) {
            int ch  = t + 512 * j;
            int c   = ch >> 3;        // mirror-row = our column
            int tt  = ch & 7;
            float s = Ks[tt * KSTR + c];
            #pragma unroll
            for (int q = 1; q < 16; ++q) s += Ks[(tt + 8 * q) * KSTR + c];
            float p;
            p = __shfl_xor(s, 1); s = s + p;
            p = __shfl_xor(s, 2); s = s + p;
            p = __shfl_xor(s, 4); s = s + p;
            mleaf[j] = s;
        }
        if ((t & 7) == 0) {
            int rb = t >> 3;
            #pragma unroll
            for (int j = 0; j < 2; ++j) {
                int row = rb + 64 * j;
                leafs[((size_t)zz * 64 + by) * 8192 + brow + row] = mleaf[j];
            }
        }
    }
}

// ---- fused reduction (unchanged from R14/R16)
__global__ void reduce_kernel(const float* __restrict__ leafs, float* __restrict__ rowsums,
                              unsigned* __restrict__ cnt, float* __restrict__ out) {
    __shared__ float L[256];
    __shared__ float M[3];
    __shared__ int lastFlag;
    const int t = threadIdx.x;
    const int tid = blockIdx.x * 256 + t;
    const int z = tid >> 13;
    const int r = tid & 8191;

    const float* base = leafs + ((size_t)z * 64) * 8192 + r;
    float v[64];
    #pragma unroll
    for (int cbi = 0; cbi < 64; ++cbi) v[cbi] = base[(size_t)cbi * 8192];
    #pragma unroll
    for (int n = 32; n >= 1; n >>= 1)
        #pragma unroll
        for (int i = 0; i < 64; ++i)
            if (i < n) v[i] = v[2*i] + v[2*i+1];
    rowsums[tid] = v[0];

    __threadfence();
    if (t == 0) {
        unsigned old = atomicAdd(cnt, 1u);
        lastFlag = (old == 95u) ? 1 : 0;
    }
    __syncthreads();
    if (!lastFlag) return;
    __threadfence();

    for (int zz = 0; zz < 3; ++zz) {
        const float4* src = (const float4*)(rowsums + zz * 8192);
        float w[32];
        #pragma unroll
        for (int i = 0; i < 8; ++i) {
            float4 q = src[t * 8 + i];
            w[4*i+0] = q.x; w[4*i+1] = q.y; w[4*i+2] = q.z; w[4*i+3] = q.w;
        }
        #pragma unroll
        for (int n = 16; n >= 1; n >>= 1)
            #pragma unroll
            for (int i = 0; i < 32; ++i)
                if (i < n) w[i] = w[2*i] + w[2*i+1];
        L[t] = w[0];
        __syncthreads();
        for (int n = 128; n >= 1; n >>= 1) {
            float u = 0.f;
            if (t < n) u = L[2*t] + L[2*t+1];
            __syncthreads();
            if (t < n) L[t] = u;
            __syncthreads();
        }
        if (t == 0) M[zz] = L[0] * (1.0f / 67108864.0f);
        __syncthreads();
    }
    if (t == 0) {
        float t1 = M[0] + M[1];
        out[0] = t1 - 2.0f * M[2];
    }
}

extern "C" void kernel_launch(void* const* d_in, const int* in_sizes, int n_in,
                              void* d_out, int out_size, void* d_ws, size_t ws_size,
                              hipStream_t stream) {
    const float* x = (const float*)d_in[0];
    const float* y = (const float*)d_in[1];
    float* wsf     = (float*)d_ws;
    float* leafs   = wsf + LEAF_F;
    float* rowsums = wsf + ROWS_F;
    unsigned* cnt  = (unsigned*)(wsf + CNT_F);
    float* nx      = wsf + NX_F;
    float* ny      = wsf + NY_F;
    unsigned short* Xh = (unsigned short*)(wsf + SPLIT_F);
    unsigned short* Xl = Xh + SPLIT_ELEMS;
    unsigned short* Yh = Xl + SPLIT_ELEMS;
    unsigned short* Yl = Yh + SPLIT_ELEMS;

    prep_kernel<<<64, 256, 0, stream>>>(x, y, Xh, Xl, Yh, Yl, nx, ny, cnt);
    dim3 grid(65, 64, 2);
    mmd_tile_kernel<<<grid, 512, 0, stream>>>(Xh, Xl, Yh, Yl, nx, ny, leafs);
    reduce_kernel<<<96, 256, 0, stream>>>(leafs, rowsums, cnt, (float*)d_out);
}

// Round 18
// 150.467 us; speedup vs baseline: 1.0712x; 1.0712x over previous
//
#include <hip/hip_runtime.h>
#include <cmath>

#define NPTS 8192
#define DIM 64
#define BT 128
#define KSTR 132         // float word stride per ROW of Ks (row-major)

// ws layout (float offsets)
#define LEAF_F   0
#define LEAF_N   (3 * 8192 * 64)          // layout [z][cb][row]
#define ROWS_F   (LEAF_F + LEAF_N)
#define ROWS_N   (3 * 8192)
#define MEANS_F  (ROWS_F + ROWS_N)
#define NX_F     ((MEANS_F + 3 + 3) & ~3) // 16B-align
#define NY_F     (NX_F + 8192)
#define SPLIT_F  (NY_F + 8192)
#define SPLIT_ELEMS (NPTS * DIM)

// frag-major split layout: [rowtile t16][kc 0..1][quad 0..3][mrow 0..15][8]

typedef short bf16x8 __attribute__((ext_vector_type(8)));
typedef float f32x4  __attribute__((ext_vector_type(4)));
typedef float f32x2  __attribute__((ext_vector_type(2)));

__device__ __forceinline__ unsigned short f32_bf16_rne(float f) {
    unsigned u = __float_as_uint(f);
    return (unsigned short)((u + 0x7FFFu + ((u >> 16) & 1u)) >> 16);
}
__device__ __forceinline__ float bf16_f32(unsigned short h) {
    return __uint_as_float(((unsigned)h) << 16);
}

// ---- fused prep (64x256): bf16 hi/lo split (frag-major) + norms
__global__ void prep_kernel(const float* __restrict__ x, const float* __restrict__ y,
                            unsigned short* __restrict__ Xh, unsigned short* __restrict__ Xl,
                            unsigned short* __restrict__ Yh, unsigned short* __restrict__ Yl,
                            float* __restrict__ nx, float* __restrict__ ny) {
    int r = blockIdx.x * 256 + threadIdx.x;   // 0..16383
    int isY = r >= NPTS;
    int rr = isY ? r - NPTS : r;
    const float4* Rg = (const float4*)((isY ? y : x) + (size_t)rr * DIM);
    unsigned short* Hh = isY ? Yh : Xh;
    unsigned short* Hl = isY ? Yl : Xl;
    const int t16 = rr >> 4, mrow = rr & 15;
    float s = 0.f;
    #pragma unroll
    for (int k4 = 0; k4 < 16; ++k4) {
        float4 v = Rg[k4];
        ushort4 h, l;
        h.x = f32_bf16_rne(v.x); l.x = f32_bf16_rne(v.x - bf16_f32(h.x));
        h.y = f32_bf16_rne(v.y); l.y = f32_bf16_rne(v.y - bf16_f32(h.y));
        h.z = f32_bf16_rne(v.z); l.z = f32_bf16_rne(v.z - bf16_f32(h.z));
        h.w = f32_bf16_rne(v.w); l.w = f32_bf16_rne(v.w - bf16_f32(h.w));
        int off = t16 * 1024 + (k4 >> 3) * 512 + ((k4 >> 1) & 3) * 128 + mrow * 8 + (k4 & 1) * 4;
        *(ushort4*)(Hh + off) = h;
        *(ushort4*)(Hl + off) = l;
        s = fmaf(v.x, v.x, s); s = fmaf(v.y, v.y, s);
        s = fmaf(v.z, v.z, s); s = fmaf(v.w, v.w, s);
    }
    if (isY) ny[rr] = s; else nx[rr] = s;
}

// ---- main tile kernel: identical to R17 (best tile, known-passing bits)
__global__ __launch_bounds__(512, 4) void mmd_tile_kernel(
    const unsigned short* __restrict__ Xh, const unsigned short* __restrict__ Xl,
    const unsigned short* __restrict__ Yh, const unsigned short* __restrict__ Yl,
    const float* __restrict__ nx, const float* __restrict__ ny,
    float* __restrict__ leafs)
{
    const int gi = blockIdx.x;             // 0..64
    const int gj = blockIdx.y;             // 0..63
    int zz, bx, by;
    if (blockIdx.z == 1) {
        if (gi >= 64) return;
        zz = 2; bx = gi; by = gj;
    } else if (gi > gj) {
        zz = 0; by = gj; bx = gi - 1;
    } else {
        zz = 1; by = gi; bx = gj;
    }

    __shared__ __align__(16) float Ks[128 * KSTR];   // row-major: Ks[row*KSTR+col]
    __shared__ float sqA[BT];
    __shared__ float sqB[BT];

    const int t = threadIdx.x;
    const size_t arow = (size_t)by * BT;
    const size_t brow = (size_t)bx * BT;
    const int cb = bx;

    const unsigned short* pAh = (zz == 1) ? Yh : Xh;
    const unsigned short* pAl = (zz == 1) ? Yl : Xl;
    const unsigned short* pBh = (zz == 0) ? Xh : Yh;
    const unsigned short* pBl = (zz == 0) ? Xl : Yl;

    if (t < 256) {
        const float* nA = (zz == 1) ? ny : nx;
        const float* nB = (zz == 0) ? nx : ny;
        if (t < BT) sqA[t] = nA[arow + t];
        else        sqB[t - BT] = nB[brow + t - BT];
    }
    __syncthreads();

    const int lane = t & 63;
    const int wv   = t >> 6;               // 0..7
    const int mrow = lane & 15;
    const int quad = lane >> 4;
    const int rblk = (wv & 3) << 5;        // 0,32,64,96
    const int cblk = (wv >> 2) << 6;       // 0,64

    const int aT = by * 8 + (wv & 3) * 2;
    const int bT = bx * 8 + (wv >> 2) * 4;
    const int lsub = quad * 128 + mrow * 8;

    bf16x8 fAh[2][2], fAl[2][2];
    #pragma unroll
    for (int rt = 0; rt < 2; ++rt)
        #pragma unroll
        for (int kc = 0; kc < 2; ++kc) {
            int off = (aT + rt) * 1024 + kc * 512 + lsub;
            fAh[rt][kc] = *(const bf16x8*)(pAh + off);
            fAl[rt][kc] = *(const bf16x8*)(pAl + off);
        }

    f32x4 acc[2][4];
    #pragma unroll
    for (int rt = 0; rt < 2; ++rt)
        #pragma unroll
        for (int ct = 0; ct < 4; ++ct)
            acc[rt][ct] = (f32x4){0.f, 0.f, 0.f, 0.f};

    #pragma unroll
    for (int ct = 0; ct < 4; ++ct) {
        int boff = (bT + ct) * 1024 + lsub;
        bf16x8 bh0 = *(const bf16x8*)(pBh + boff);
        bf16x8 bh1 = *(const bf16x8*)(pBh + boff + 512);
        bf16x8 bl0 = *(const bf16x8*)(pBl + boff);
        bf16x8 bl1 = *(const bf16x8*)(pBl + boff + 512);
        #pragma unroll
        for (int rt = 0; rt < 2; ++rt) {
            f32x4 c = acc[rt][ct];
            // identical 6-pass order per accumulator as R8-R17
            c = __builtin_amdgcn_mfma_f32_16x16x32_bf16(fAh[rt][0], bh0, c, 0, 0, 0);
            c = __builtin_amdgcn_mfma_f32_16x16x32_bf16(fAh[rt][0], bl0, c, 0, 0, 0);
            c = __builtin_amdgcn_mfma_f32_16x16x32_bf16(fAl[rt][0], bh0, c, 0, 0, 0);
            c = __builtin_amdgcn_mfma_f32_16x16x32_bf16(fAh[rt][1], bh1, c, 0, 0, 0);
            c = __builtin_amdgcn_mfma_f32_16x16x32_bf16(fAh[rt][1], bl1, c, 0, 0, 0);
            c = __builtin_amdgcn_mfma_f32_16x16x32_bf16(fAl[rt][1], bh1, c, 0, 0, 0);
            acc[rt][ct] = c;
        }
    }

    // ---- epilogue: k = exp2f(sqd * -log2e/4096)
    const float SCL = (float)(-1.4426950408889634 / 4096.0);
    #pragma unroll
    for (int rt = 0; rt < 2; ++rt)
        #pragma unroll
        for (int ct = 0; ct < 4; ++ct)
            #pragma unroll
            for (int i = 0; i < 4; ++i) {
                int row = rblk + rt * 16 + quad * 4 + i;
                int col = cblk + ct * 16 + mrow;
                float d  = acc[rt][ct][i];
                float s2 = sqA[row] + sqB[col];
                float sqd = s2 - 2.0f * d;
                Ks[row * KSTR + col] = exp2f(sqd * SCL);
            }
    __syncthreads();

    // ---- row chains, paired b64 (R17): in-thread add = numpy tree level 1
    {
        int row = t >> 2;             // 0..127
        int tp  = t & 3;              // chain pair 0..3 (tt = 2tp, 2tp+1)
        const float* base = &Ks[row * KSTR + 2 * tp];
        f32x2 v0 = *(const f32x2*)base;
        float se = v0.x, so = v0.y;
        #pragma unroll
        for (int q = 1; q < 16; ++q) {
            f32x2 v = *(const f32x2*)(base + 8 * q);
            se += v.x; so += v.y;
        }
        float s01 = se + so;
        float p;
        p = __shfl_xor(s01, 1); float s = s01 + p;
        p = __shfl_xor(s, 2);   s = s + p;
        if (tp == 0)
            leafs[((size_t)zz * 64 + cb) * 8192 + arow + row] = s;
    }

    // ---- mirror tile's leaf sums (column chains, bitwise-symmetric matrix)
    if (zz < 2 && bx > by) {
        float mleaf[2];
        #pragma unroll
        for (int j = 0; j < 2; ++j) {
            int ch  = t + 512 * j;
            int c   = ch >> 3;        // mirror-row = our column
            int tt  = ch & 7;
            float s = Ks[tt * KSTR + c];
            #pragma unroll
            for (int q = 1; q < 16; ++q) s += Ks[(tt + 8 * q) * KSTR + c];
            float p;
            p = __shfl_xor(s, 1); s = s + p;
            p = __shfl_xor(s, 2); s = s + p;
            p = __shfl_xor(s, 4); s = s + p;
            mleaf[j] = s;
        }
        if ((t & 7) == 0) {
            int rb = t >> 3;
            #pragma unroll
            for (int j = 0; j < 2; ++j) {
                int row = rb + 64 * j;
                leafs[((size_t)zz * 64 + by) * 8192 + brow + row] = mleaf[j];
            }
        }
    }
}

// Phase B: per row, balanced binary tree over its 64 leaf sums (cb ascending)
__global__ void rowsum_kernel(const float* __restrict__ leafs, float* __restrict__ rowsums) {
    const int t = threadIdx.x;
    const int tid = blockIdx.x * 256 + t;    // 0..24575
    const int z = tid >> 13;
    const int r = tid & 8191;
    const float* base = leafs + ((size_t)z * 64) * 8192 + r;
    float v[64];
    #pragma unroll
    for (int cbi = 0; cbi < 64; ++cbi) v[cbi] = base[(size_t)cbi * 8192];
    #pragma unroll
    for (int n = 32; n >= 1; n >>= 1)
        #pragma unroll
        for (int i = 0; i < 64; ++i)
            if (i < n) v[i] = v[2*i] + v[2*i+1];
    rowsums[tid] = v[0];
}

// Phase C: per matrix, balanced tree over 8192 row sums; /2^26 exact
__global__ void colsum_kernel(const float* __restrict__ rowsums, float* __restrict__ means) {
    __shared__ float L[256];
    const int z = blockIdx.x;
    const int t = threadIdx.x;
    const float4* src = (const float4*)(rowsums + z * 8192);
    float w[32];
    #pragma unroll
    for (int i = 0; i < 8; ++i) {
        float4 q = src[t * 8 + i];
        w[4*i+0] = q.x; w[4*i+1] = q.y; w[4*i+2] = q.z; w[4*i+3] = q.w;
    }
    #pragma unroll
    for (int n = 16; n >= 1; n >>= 1)
        #pragma unroll
        for (int i = 0; i < 32; ++i)
            if (i < n) w[i] = w[2*i] + w[2*i+1];
    L[t] = w[0];
    __syncthreads();
    for (int n = 128; n >= 1; n >>= 1) {
        float u = 0.f;
        if (t < n) u = L[2*t] + L[2*t+1];
        __syncthreads();
        if (t < n) L[t] = u;
        __syncthreads();
    }
    if (t == 0) means[z] = L[0] * (1.0f / 67108864.0f);
}

// Phase D: fp32 combine in reference expression order
__global__ void combine_kernel(const float* __restrict__ means, float* __restrict__ out) {
    float t1 = means[0] + means[1];
    out[0] = t1 - 2.0f * means[2];
}

extern "C" void kernel_launch(void* const* d_in, const int* in_sizes, int n_in,
                              void* d_out, int out_size, void* d_ws, size_t ws_size,
                              hipStream_t stream) {
    const float* x = (const float*)d_in[0];
    const float* y = (const float*)d_in[1];
    float* wsf     = (float*)d_ws;
    float* leafs   = wsf + LEAF_F;
    float* rowsums = wsf + ROWS_F;
    float* means   = wsf + MEANS_F;
    float* nx      = wsf + NX_F;
    float* ny      = wsf + NY_F;
    unsigned short* Xh = (unsigned short*)(wsf + SPLIT_F);
    unsigned short* Xl = Xh + SPLIT_ELEMS;
    unsigned short* Yh = Xl + SPLIT_ELEMS;
    unsigned short* Yl = Yh + SPLIT_ELEMS;

    prep_kernel<<<64, 256, 0, stream>>>(x, y, Xh, Xl, Yh, Yl, nx, ny);
    dim3 grid(65, 64, 2);
    mmd_tile_kernel<<<grid, 512, 0, stream>>>(Xh, Xl, Yh, Yl, nx, ny, leafs);
    rowsum_kernel<<<96, 256, 0, stream>>>(leafs, rowsums);
    colsum_kernel<<<3, 256, 0, stream>>>(rowsums, means);
    combine_kernel<<<1, 1, 0, stream>>>(means, (float*)d_out);
}